// Round 9
// baseline (1010.410 us; speedup 1.0000x reference)
//
#include <hip/hip_runtime.h>
#include <hip/hip_bf16.h>
#include <stdint.h>

typedef __attribute__((ext_vector_type(8))) short short8;
typedef __attribute__((ext_vector_type(4))) short short4v;
typedef __attribute__((ext_vector_type(4))) float floatx4;
typedef unsigned long long u64;

typedef __attribute__((address_space(1))) const uint32_t ga_u32;
typedef __attribute__((address_space(3))) uint32_t ls_u32;

static constexpr int NROWS = 32768;
static constexpr int NCODE = 8192;
static constexpr int QELEMS = 8388608;

static __device__ __forceinline__ short bf16bits(float v) {
  __hip_bfloat16 h = __float2bfloat16(v);
  return *reinterpret_cast<short*>(&h);
}

// ---- fused prep: [0,1024) z-transpose, [1024,3072) codebook, [3072,3088) amin init ----
__global__ __launch_bounds__(256) void prep_all(
    const float* __restrict__ z, const float* __restrict__ cb,
    __hip_bfloat16* __restrict__ zh, __hip_bfloat16* __restrict__ chv,
    float* __restrict__ norms, u64* __restrict__ amin)
{
  const int bid = blockIdx.x;
  const int t = threadIdx.x;
  if (bid < 1024) {
    __shared__ float tile[32][260];
    const int b = bid & 31, db = (bid >> 5) & 7, hwb = bid >> 8;
    const int d0 = db * 32, hw0 = hwb * 256;
    const float* src = z + (((size_t)b * 256 + d0) << 10) + hw0;
#pragma unroll
    for (int i = 0; i < 8; ++i) {
      int idx = i * 256 + t;
      int r = idx >> 6, c4 = (idx & 63) * 4;
      *(floatx4*)&tile[r][c4] = *(const floatx4*)&src[((size_t)r << 10) + c4];
    }
    __syncthreads();
    const int dq = t & 3;
    const int hb = t >> 2;
#pragma unroll
    for (int it = 0; it < 4; ++it) {
      int h = hb + it * 64;
      short8 o;
#pragma unroll
      for (int i = 0; i < 8; ++i) o[i] = bf16bits(tile[dq * 8 + i][h]);
      *(short8*)&zh[((size_t)(b * 1024 + hw0 + h)) * 256 + d0 + dq * 8] = o;
    }
  } else if (bid < 3072) {
    const int k = (bid - 1024) * 4 + (t >> 6);
    const int lane = t & 63;
    floatx4 v = *(const floatx4*)&cb[((size_t)k << 8) + lane * 4];
    short4v o;
#pragma unroll
    for (int i = 0; i < 4; ++i) o[i] = bf16bits(v[i]);
    *(short4v*)&chv[((size_t)k << 8) + lane * 4] = o;
    float s = v[0] * v[0] + v[1] * v[1] + v[2] * v[2] + v[3] * v[3];
#pragma unroll
    for (int off = 32; off; off >>= 1) s += __shfl_down(s, off);
    if (lane == 0) norms[k] = s;
  } else {
    const int base = (bid - 3072) * 2048;
#pragma unroll
    for (int i = 0; i < 8; ++i) amin[base + i * 256 + t] = ~0ull;
  }
}

// ---- main: 256x256 tile, 4 waves x (128x128 wave tile, acc[8][8]=256 AGPR) ----
// BK=32, 2-slot LDS (64 KiB), 2 wg/CU. Per kt: 16 ds_read + 64 MFMA per wave.
// Counted vmcnt(8): stage(kt+2) issued each kt, boundary drains stage(kt+1).
// Slot-reuse safety: lgkmcnt(0) BEFORE mid-kt barrier (frags in regs), then
// stage(kt+2) may rewrite the just-read slot.
__global__ __launch_bounds__(256, 2) void gemm_argmin(
    const __hip_bfloat16* __restrict__ zh, const __hip_bfloat16* __restrict__ chv,
    const float* __restrict__ norms, u64* __restrict__ amin)
{
  // slot s (16384 ushorts = 32 KiB): A[256][32] at s*16384, B[256][32] at +8192
  __shared__ alignas(16) unsigned short lds[2 * 16384];

  const int tid = threadIdx.x;
  const int lane = tid & 63;
  const int wid = tid >> 6;
  const int wm = wid >> 1;  // code half (128 codes)
  const int wn = wid & 1;   // zrow half (128 zrows)

  // XCD chunked swizzle: nwg = 4096 (%8 == 0)
  const int bid = blockIdx.x;
  const int swz = (bid & 7) * 512 + (bid >> 3);
  const int cx = swz & 31;   // 32 code blocks
  const int cy = swz >> 5;   // 128 zrow blocks
  const int m0 = cx * 256;
  const int n0 = cy * 256;

  const int q = lane & 15;
  const int g = lane >> 4;
  const int rchunk = ((g ^ ((q >> 1) & 3)) << 3);  // swizzled 16B chunk (ushort units)

  // staging: linear LDS dest (tid*16B + p*4KB), chunk-XOR pre-swizzled source
  const int stRow = tid >> 2;                               // 0..63
  const int stKoff = (((tid & 3) ^ ((tid >> 3) & 3)) << 3); // swizzled k-elem offset

  floatx4 acc[8][8];  // [code frag i][zrow frag j]
#pragma unroll
  for (int i = 0; i < 8; ++i)
#pragma unroll
    for (int j = 0; j < 8; ++j)
      acc[i][j] = (floatx4){0.f, 0.f, 0.f, 0.f};

  auto STAGE = [&](int kt) {  // 8 x global_load_lds(16B): A 16KB + B 16KB
    if (kt >= 8) return;
    const int slot = kt & 1;
    unsigned short* sA = lds + slot * 16384 + tid * 8;
    unsigned short* sB = sA + 8192;
#pragma unroll
    for (int p = 0; p < 4; ++p) {
      int r = stRow + p * 64;
      const __hip_bfloat16* gA = chv + ((size_t)(m0 + r) << 8) + kt * 32 + stKoff;
      __builtin_amdgcn_global_load_lds((ga_u32*)gA, (ls_u32*)(sA + p * 2048), 16, 0, 0);
      const __hip_bfloat16* gB = zh + ((size_t)(n0 + r) << 8) + kt * 32 + stKoff;
      __builtin_amdgcn_global_load_lds((ga_u32*)gB, (ls_u32*)(sB + p * 2048), 16, 0, 0);
    }
  };

  // prologue: stage kt0, kt1; drain kt0 (kt1's 8 stay in flight)
  STAGE(0); STAGE(1);
  asm volatile("s_waitcnt vmcnt(8)" ::: "memory");
  __builtin_amdgcn_s_barrier();
  asm volatile("" ::: "memory");

#pragma unroll
  for (int kt = 0; kt < 8; ++kt) {
    const int slot = kt & 1;
    short8 af[8], bf[8];
#pragma unroll
    for (int i = 0; i < 8; ++i) {
      int row = wm * 128 + i * 16 + q;
      af[i] = *(const short8*)(lds + slot * 16384 + row * 32 + rchunk);
    }
#pragma unroll
    for (int j = 0; j < 8; ++j) {
      int row = wn * 128 + j * 16 + q;
      bf[j] = *(const short8*)(lds + slot * 16384 + 8192 + row * 32 + rchunk);
    }
    asm volatile("s_waitcnt lgkmcnt(0)" ::: "memory");  // frags in regs
    __builtin_amdgcn_sched_barrier(0);
    __builtin_amdgcn_s_barrier();                       // slot now safe to rewrite
    asm volatile("" ::: "memory");
    STAGE(kt + 2);                                      // lands into slot[kt&1]
    __builtin_amdgcn_s_setprio(1);
#pragma unroll
    for (int i = 0; i < 8; ++i)
#pragma unroll
      for (int j = 0; j < 8; ++j)
        acc[i][j] = __builtin_amdgcn_mfma_f32_16x16x32_bf16(af[i], bf[j], acc[i][j], 0, 0, 0);
    __builtin_amdgcn_s_setprio(0);
    // boundary: drain stage(kt+1) (8 loads), keep stage(kt+2)'s 8 in flight
    if (kt < 6)       asm volatile("s_waitcnt vmcnt(8)" ::: "memory");
    else if (kt == 6) asm volatile("s_waitcnt vmcnt(0)" ::: "memory");
    if (kt < 7) {
      asm volatile("" ::: "memory");
      __builtin_amdgcn_s_barrier();
      asm volatile("" ::: "memory");
    }
  }

  __syncthreads();  // all waves past final reads before LDS reuse

  // ---- epilogue: fused argmin; ties -> smallest code; atomicMin (order-independent) ----
  float nrm[8][4];
#pragma unroll
  for (int i = 0; i < 8; ++i)
#pragma unroll
    for (int r = 0; r < 4; ++r)
      nrm[i][r] = norms[m0 + wm * 128 + i * 16 + g * 4 + r];

  u64* best2 = (u64*)lds;  // [256 zrows][2 wm]
#pragma unroll
  for (int j = 0; j < 8; ++j) {
    float best = __builtin_inff();
    int bc = 0;
    // ascending code order => strict < keeps smallest code on ties
#pragma unroll
    for (int i = 0; i < 8; ++i)
#pragma unroll
      for (int r = 0; r < 4; ++r) {
        float sc = fmaf(acc[i][j][r], -2.0f, nrm[i][r]);
        int cd = m0 + wm * 128 + i * 16 + g * 4 + r;
        if (sc < best) { best = sc; bc = cd; }
      }
    uint32_t u = __float_as_uint(best);
    u ^= ((uint32_t)((int32_t)u >> 31) | 0x80000000u);  // monotone-sortable
    u64 p = ((u64)u << 32) | (uint32_t)bc;
#pragma unroll
    for (int off = 16; off < 64; off <<= 1) {
      u64 o = (u64)__shfl_xor((long long)p, off);
      p = o < p ? o : p;
    }
    if (lane < 16) best2[(size_t)(wn * 128 + j * 16 + lane) * 2 + wm] = p;
  }
  __syncthreads();
  {
    u64 a = best2[tid * 2], b = best2[tid * 2 + 1];
    u64 p = a < b ? a : b;
    atomicMin(&amin[n0 + tid], p);
  }
}

// ---- gather + output + per-block loss partials (8 elems/thread, amin direct) ----
__global__ __launch_bounds__(256) void gather_out(
    const float* __restrict__ z, const float* __restrict__ cb,
    const u64* __restrict__ amin,
    float* __restrict__ out, float* __restrict__ partial)
{
  const int t = threadIdx.x;
  const size_t e0 = ((size_t)blockIdx.x * 256 + t) * 8;
  const int d = (int)((e0 >> 10) & 255);
  const int b = (int)(e0 >> 18);
  const int n0 = b * 1024 + (int)(e0 & 1023);
  uint32_t kv[8];
#pragma unroll
  for (int m = 0; m < 8; ++m) kv[m] = (uint32_t)amin[n0 + m];
  floatx4 z0 = *(const floatx4*)&z[e0];
  floatx4 z1 = *(const floatx4*)&z[e0 + 4];
  floatx4 q0, q1;
#pragma unroll
  for (int m = 0; m < 4; ++m) {
    q0[m] = cb[((size_t)kv[m] << 8) + d];
    q1[m] = cb[((size_t)kv[4 + m] << 8) + d];
  }
  *(floatx4*)&out[e0] = q0;
  *(floatx4*)&out[e0 + 4] = q1;
  float s = 0.f;
#pragma unroll
  for (int m = 0; m < 4; ++m) {
    float d0 = z0[m] - q0[m], d1 = z1[m] - q1[m];
    s += d0 * d0 + d1 * d1;
  }
#pragma unroll
  for (int off = 32; off; off >>= 1) s += __shfl_down(s, off);
  __shared__ float ps[4];
  if ((t & 63) == 0) ps[t >> 6] = s;
  __syncthreads();
  if (t == 0) partial[blockIdx.x] = ps[0] + ps[1] + ps[2] + ps[3];
}

// ---- deterministic final reduction + scalar outputs ----
__global__ __launch_bounds__(256) void finalize(const float* __restrict__ partial,
                                                float* __restrict__ out)
{
  const int t = threadIdx.x;
  float s = 0.f;
#pragma unroll
  for (int i = 0; i < 16; ++i) s += partial[i * 256 + t];
#pragma unroll
  for (int off = 32; off; off >>= 1) s += __shfl_down(s, off);
  __shared__ float ps[4];
  if ((t & 63) == 0) ps[t >> 6] = s;
  __syncthreads();
  if (t == 0) {
    float m = (ps[0] + ps[1] + ps[2] + ps[3]) / (float)QELEMS;
    out[QELEMS] = m;             // codebook_loss
    out[QELEMS + 1] = 0.2f * m;  // commitment_loss
  }
}

extern "C" void kernel_launch(void* const* d_in, const int* in_sizes, int n_in,
                              void* d_out, int out_size, void* d_ws, size_t ws_size,
                              hipStream_t stream)
{
  const float* z = (const float*)d_in[0];
  const float* cb = (const float*)d_in[1];
  float* out = (float*)d_out;
  char* ws = (char*)d_ws;

  // ws layout (bytes)
  __hip_bfloat16* zh = (__hip_bfloat16*)(ws + 0);          // 16,777,216
  __hip_bfloat16* chv = (__hip_bfloat16*)(ws + 16777216);  //  4,194,304
  float* norms = (float*)(ws + 20971520);                  //    131,072 (padded)
  u64* amin = (u64*)(ws + 21102592);                       //    262,144
  float* lpart = (float*)(ws + 21364736);                  //     16,384
  // total: 21,381,120 bytes

  prep_all<<<3088, 256, 0, stream>>>(z, cb, zh, chv, norms, amin);
  gemm_argmin<<<4096, 256, 0, stream>>>(zh, chv, norms, amin);
  gather_out<<<QELEMS / 2048, 256, 0, stream>>>(z, cb, amin, out, lpart);
  finalize<<<1, 256, 0, stream>>>(lpart, out);
}

// Round 10
// 517.521 us; speedup vs baseline: 1.9524x; 1.9524x over previous
//
#include <hip/hip_runtime.h>
#include <hip/hip_bf16.h>
#include <stdint.h>

typedef __attribute__((ext_vector_type(8))) short short8;
typedef __attribute__((ext_vector_type(4))) short short4v;
typedef __attribute__((ext_vector_type(4))) float floatx4;
typedef unsigned long long u64;

typedef __attribute__((address_space(1))) const uint32_t ga_u32;
typedef __attribute__((address_space(3))) uint32_t ls_u32;

static constexpr int NROWS = 32768;
static constexpr int NCODE = 8192;
static constexpr int QELEMS = 8388608;

static __device__ __forceinline__ short bf16bits(float v) {
  __hip_bfloat16 h = __float2bfloat16(v);
  return *reinterpret_cast<short*>(&h);
}

// ---- fused prep: [0,1024) z-transpose, [1024,3072) codebook, [3072,3088) amin init ----
__global__ __launch_bounds__(256) void prep_all(
    const float* __restrict__ z, const float* __restrict__ cb,
    __hip_bfloat16* __restrict__ zh, __hip_bfloat16* __restrict__ chv,
    float* __restrict__ norms, u64* __restrict__ amin)
{
  const int bid = blockIdx.x;
  const int t = threadIdx.x;
  if (bid < 1024) {
    __shared__ float tile[32][260];
    const int b = bid & 31, db = (bid >> 5) & 7, hwb = bid >> 8;
    const int d0 = db * 32, hw0 = hwb * 256;
    const float* src = z + (((size_t)b * 256 + d0) << 10) + hw0;
#pragma unroll
    for (int i = 0; i < 8; ++i) {
      int idx = i * 256 + t;
      int r = idx >> 6, c4 = (idx & 63) * 4;
      *(floatx4*)&tile[r][c4] = *(const floatx4*)&src[((size_t)r << 10) + c4];
    }
    __syncthreads();
    const int dq = t & 3;
    const int hb = t >> 2;
#pragma unroll
    for (int it = 0; it < 4; ++it) {
      int h = hb + it * 64;
      short8 o;
#pragma unroll
      for (int i = 0; i < 8; ++i) o[i] = bf16bits(tile[dq * 8 + i][h]);
      *(short8*)&zh[((size_t)(b * 1024 + hw0 + h)) * 256 + d0 + dq * 8] = o;
    }
  } else if (bid < 3072) {
    const int k = (bid - 1024) * 4 + (t >> 6);
    const int lane = t & 63;
    floatx4 v = *(const floatx4*)&cb[((size_t)k << 8) + lane * 4];
    short4v o;
#pragma unroll
    for (int i = 0; i < 4; ++i) o[i] = bf16bits(v[i]);
    *(short4v*)&chv[((size_t)k << 8) + lane * 4] = o;
    float s = v[0] * v[0] + v[1] * v[1] + v[2] * v[2] + v[3] * v[3];
#pragma unroll
    for (int off = 32; off; off >>= 1) s += __shfl_down(s, off);
    if (lane == 0) norms[k] = s;
  } else {
    const int base = (bid - 3072) * 2048;
#pragma unroll
    for (int i = 0; i < 8; ++i) amin[base + i * 256 + t] = ~0ull;
  }
}

// ---- main: persistent 1 block/CU; 4 waves x 128x128 wave tile (acc[8][8]) ----
// Block owns code panel m0 (constant), loops 16 zrow tiles. 128-step pipelined
// K-chain: body sg = {STAGE(sg+3) | RD frags(sg+1) -> other bank | 64 MFMA(sg)
// | lgkmcnt(0) | vmcnt(8) | barrier}. 3-slot LDS ring; per-tile argmin epilogue
// overlaps in-flight stages.
__global__ __launch_bounds__(256, 1) void gemm_argmin(
    const __hip_bfloat16* __restrict__ zh, const __hip_bfloat16* __restrict__ chv,
    const float* __restrict__ norms, u64* __restrict__ amin)
{
  // 3 slots x 32 KiB (A[256][32] + B[256][32] per slot) + 4 KiB best2
  __shared__ alignas(16) unsigned short lds[3 * 16384 + 2048];

  const int tid = threadIdx.x;
  const int lane = tid & 63;
  const int wid = tid >> 6;
  const int wm = wid >> 1;  // code half (128 codes)
  const int wn = wid & 1;   // zrow half (128 zrows)

  const int bid = blockIdx.x;     // 256 blocks: xcd = bid&7, code panel = bid>>3
  const int xcd = bid & 7;
  const int m0 = (bid >> 3) * 256;

  const int q = lane & 15;
  const int g = lane >> 4;
  const int rchunk = ((g ^ ((q >> 1) & 3)) << 3);  // swizzled 16B chunk (ushort units)

  // staging: linear LDS dest, chunk-XOR pre-swizzled global source (verified r9)
  const int stRow = tid >> 2;                               // 0..63
  const int stKoff = (((tid & 3) ^ ((tid >> 3) & 3)) << 3); // swizzled k-elem offset

  floatx4 acc[8][8];
#pragma unroll
  for (int i = 0; i < 8; ++i)
#pragma unroll
    for (int j = 0; j < 8; ++j)
      acc[i][j] = (floatx4){0.f, 0.f, 0.f, 0.f};

  auto STAGE = [&](int s) {  // stage K-step s (global, 0..127): 8 x 16B loads
    const int slot = s % 3;
    const int kpos = (s & 7) << 5;
    const int n0s = ((xcd << 4) + (s >> 3)) << 8;
    unsigned short* sA = lds + slot * 16384 + tid * 8;
    unsigned short* sB = sA + 8192;
#pragma unroll
    for (int p = 0; p < 4; ++p) {
      int r = stRow + p * 64;
      const __hip_bfloat16* gA = chv + ((size_t)(m0 + r) << 8) + kpos + stKoff;
      __builtin_amdgcn_global_load_lds((ga_u32*)gA, (ls_u32*)(sA + p * 2048), 16, 0, 0);
      const __hip_bfloat16* gB = zh + ((size_t)(n0s + r) << 8) + kpos + stKoff;
      __builtin_amdgcn_global_load_lds((ga_u32*)gB, (ls_u32*)(sB + p * 2048), 16, 0, 0);
    }
  };
  auto RD = [&](int s, short8 (&af)[8], short8 (&bf)[8]) {
    const int base = (s % 3) * 16384;
#pragma unroll
    for (int i = 0; i < 8; ++i)
      af[i] = *(const short8*)(lds + base + (wm * 128 + i * 16 + q) * 32 + rchunk);
#pragma unroll
    for (int j = 0; j < 8; ++j)
      bf[j] = *(const short8*)(lds + base + 8192 + (wn * 128 + j * 16 + q) * 32 + rchunk);
  };

  short8 afA[8], bfA[8], afB[8], bfB[8];

  auto BODY = [&](int sg, short8 (&afC)[8], short8 (&bfC)[8],
                  short8 (&afN)[8], short8 (&bfN)[8]) {
    if (sg + 3 < 128) STAGE(sg + 3);        // -> slot sg%3 (reads done last body)
    if (sg + 1 < 128) RD(sg + 1, afN, bfN); // overlaps MFMA below (no dep)
    __builtin_amdgcn_s_setprio(1);
#pragma unroll
    for (int i = 0; i < 8; ++i)
#pragma unroll
      for (int j = 0; j < 8; ++j)
        acc[i][j] = __builtin_amdgcn_mfma_f32_16x16x32_bf16(afC[i], bfC[j], acc[i][j], 0, 0, 0);
    __builtin_amdgcn_s_setprio(0);
    asm volatile("s_waitcnt lgkmcnt(0)" ::: "memory");  // frags(sg+1) in regs
    __builtin_amdgcn_sched_barrier(0);
    if (sg < 125)       asm volatile("s_waitcnt vmcnt(8)" ::: "memory");  // stage(sg+2) landed
    else if (sg == 125) asm volatile("s_waitcnt vmcnt(0)" ::: "memory");
    asm volatile("" ::: "memory");
    __builtin_amdgcn_s_barrier();
    asm volatile("" ::: "memory");
  };

  // prologue: stage 0,1,2; drain 0,1 (2's 8 loads stay in flight); read frags(0)
  STAGE(0); STAGE(1); STAGE(2);
  asm volatile("s_waitcnt vmcnt(8)" ::: "memory");
  __builtin_amdgcn_s_barrier();
  asm volatile("" ::: "memory");
  RD(0, afA, bfA);
  asm volatile("s_waitcnt lgkmcnt(0)" ::: "memory");
  __builtin_amdgcn_sched_barrier(0);
  __builtin_amdgcn_s_barrier();
  asm volatile("" ::: "memory");

  // norms for this block's code panel (constant across tiles)
  float nrm[8][4];
#pragma unroll
  for (int i = 0; i < 8; ++i)
#pragma unroll
    for (int r = 0; r < 4; ++r)
      nrm[i][r] = norms[m0 + wm * 128 + i * 16 + g * 4 + r];

  u64* best2 = (u64*)(lds + 3 * 16384);  // [256 zrows][2 wm], outside slot ring

#pragma unroll 1
  for (int t = 0; t < 16; ++t) {
#pragma unroll
    for (int k2 = 0; k2 < 8; k2 += 2) {
      BODY(t * 8 + k2,     afA, bfA, afB, bfB);
      BODY(t * 8 + k2 + 1, afB, bfB, afA, bfA);
    }
    // ---- epilogue tile t: fused argmin; ties -> smallest code ----
    const int n0t = ((xcd << 4) + t) << 8;
#pragma unroll
    for (int j = 0; j < 8; ++j) {
      float best = __builtin_inff();
      int bc = 0;
#pragma unroll
      for (int i = 0; i < 8; ++i)
#pragma unroll
        for (int r = 0; r < 4; ++r) {
          float sc = fmaf(acc[i][j][r], -2.0f, nrm[i][r]);
          int cd = m0 + wm * 128 + i * 16 + g * 4 + r;
          if (sc < best) { best = sc; bc = cd; }
        }
      uint32_t u = __float_as_uint(best);
      u ^= ((uint32_t)((int32_t)u >> 31) | 0x80000000u);  // monotone-sortable
      u64 p = ((u64)u << 32) | (uint32_t)bc;
#pragma unroll
      for (int off = 16; off < 64; off <<= 1) {
        u64 o = (u64)__shfl_xor((long long)p, off);
        p = o < p ? o : p;
      }
      if (lane < 16) best2[(size_t)(wn * 128 + j * 16 + lane) * 2 + wm] = p;
    }
    __syncthreads();
    {
      u64 a = best2[tid * 2], b = best2[tid * 2 + 1];
      u64 p = a < b ? a : b;
      atomicMin(&amin[n0t + tid], p);
    }
    // re-zero accumulators for next tile
#pragma unroll
    for (int i = 0; i < 8; ++i)
#pragma unroll
      for (int j = 0; j < 8; ++j)
        acc[i][j] = (floatx4){0.f, 0.f, 0.f, 0.f};
  }
}

// ---- gather + output + per-block loss partials (8 elems/thread, amin direct) ----
__global__ __launch_bounds__(256) void gather_out(
    const float* __restrict__ z, const float* __restrict__ cb,
    const u64* __restrict__ amin,
    float* __restrict__ out, float* __restrict__ partial)
{
  const int t = threadIdx.x;
  const size_t e0 = ((size_t)blockIdx.x * 256 + t) * 8;
  const int d = (int)((e0 >> 10) & 255);
  const int b = (int)(e0 >> 18);
  const int n0 = b * 1024 + (int)(e0 & 1023);
  uint32_t kv[8];
#pragma unroll
  for (int m = 0; m < 8; ++m) kv[m] = (uint32_t)amin[n0 + m];
  floatx4 z0 = *(const floatx4*)&z[e0];
  floatx4 z1 = *(const floatx4*)&z[e0 + 4];
  floatx4 q0, q1;
#pragma unroll
  for (int m = 0; m < 4; ++m) {
    q0[m] = cb[((size_t)kv[m] << 8) + d];
    q1[m] = cb[((size_t)kv[4 + m] << 8) + d];
  }
  *(floatx4*)&out[e0] = q0;
  *(floatx4*)&out[e0 + 4] = q1;
  float s = 0.f;
#pragma unroll
  for (int m = 0; m < 4; ++m) {
    float d0 = z0[m] - q0[m], d1 = z1[m] - q1[m];
    s += d0 * d0 + d1 * d1;
  }
#pragma unroll
  for (int off = 32; off; off >>= 1) s += __shfl_down(s, off);
  __shared__ float ps[4];
  if ((t & 63) == 0) ps[t >> 6] = s;
  __syncthreads();
  if (t == 0) partial[blockIdx.x] = ps[0] + ps[1] + ps[2] + ps[3];
}

// ---- deterministic final reduction + scalar outputs ----
__global__ __launch_bounds__(256) void finalize(const float* __restrict__ partial,
                                                float* __restrict__ out)
{
  const int t = threadIdx.x;
  float s = 0.f;
#pragma unroll
  for (int i = 0; i < 16; ++i) s += partial[i * 256 + t];
#pragma unroll
  for (int off = 32; off; off >>= 1) s += __shfl_down(s, off);
  __shared__ float ps[4];
  if ((t & 63) == 0) ps[t >> 6] = s;
  __syncthreads();
  if (t == 0) {
    float m = (ps[0] + ps[1] + ps[2] + ps[3]) / (float)QELEMS;
    out[QELEMS] = m;             // codebook_loss
    out[QELEMS + 1] = 0.2f * m;  // commitment_loss
  }
}

extern "C" void kernel_launch(void* const* d_in, const int* in_sizes, int n_in,
                              void* d_out, int out_size, void* d_ws, size_t ws_size,
                              hipStream_t stream)
{
  const float* z = (const float*)d_in[0];
  const float* cb = (const float*)d_in[1];
  float* out = (float*)d_out;
  char* ws = (char*)d_ws;

  // ws layout (bytes)
  __hip_bfloat16* zh = (__hip_bfloat16*)(ws + 0);          // 16,777,216
  __hip_bfloat16* chv = (__hip_bfloat16*)(ws + 16777216);  //  4,194,304
  float* norms = (float*)(ws + 20971520);                  //    131,072 (padded)
  u64* amin = (u64*)(ws + 21102592);                       //    262,144
  float* lpart = (float*)(ws + 21364736);                  //     16,384
  // total: 21,381,120 bytes

  prep_all<<<3088, 256, 0, stream>>>(z, cb, zh, chv, norms, amin);
  gemm_argmin<<<256, 256, 0, stream>>>(zh, chv, norms, amin);
  gather_out<<<QELEMS / 2048, 256, 0, stream>>>(z, cb, amin, out, lpart);
  finalize<<<1, 256, 0, stream>>>(lpart, out);
}